// Round 6
// baseline (338.026 us; speedup 1.0000x reference)
//
#include <hip/hip_runtime.h>

// VGCN layer, restructured:
//   agg[n]   = sum_{e: dst=n} norm[src] * X[src]          (bf16 gather-sum, CSR)
//   out[n]   = relu(0.5*norm[n]*(agg[n] @ W^T) + 0.5*init[n]/deg[n] + 0.5*X[n])
// R3: pipelined gather (8-deep); 1-block scan.
// R6: two-phase CSR fill. Phase 1 compacts edges into 8 dst-range bucket
//     lists with fully coalesced writes (ballot+scan compaction). Phase 2
//     reads HW_REG_XCC_ID so each XCD processes exactly its own bucket:
//     0.8MB stream + 0.8MB scatter per 4MB L2 -> dirty lines accumulate all
//     writes and evict once (WRITE_SIZE was 68MB for ~7MB of data in R5).

#define DIM 128

typedef __attribute__((ext_vector_type(8))) short short8v;   // 8 bf16 (4 VGPRs)
typedef __attribute__((ext_vector_type(4))) float f32x4;     // MFMA acc

static __device__ __forceinline__ unsigned short f2b(float f) {
    unsigned u = __float_as_uint(f);
    unsigned r = (u >> 16) & 1;          // round-to-nearest-even
    u += 0x7fffu + r;
    return (unsigned short)(u >> 16);
}

__global__ __launch_bounds__(256) void count_deg_k(const int* __restrict__ dst,
                                                   int* __restrict__ deg, int E) {
    int e = blockIdx.x * 256 + threadIdx.x;
    if (e < E) atomicAdd(&deg[__builtin_nontemporal_load(dst + e)], 1);
}

__global__ __launch_bounds__(256) void block_sums_k(const int* __restrict__ deg,
                                                    int* __restrict__ bsums, int N) {
    __shared__ int sh[256];
    int i = blockIdx.x * 256 + threadIdx.x;
    sh[threadIdx.x] = (i < N) ? deg[i] : 0;
    __syncthreads();
    for (int off = 128; off > 0; off >>= 1) {
        if (threadIdx.x < off) sh[threadIdx.x] += sh[threadIdx.x + off];
        __syncthreads();
    }
    if (threadIdx.x == 0) bsums[blockIdx.x] = sh[0];
}

// one block of 512 threads: exclusive scan of nb (<=512) block sums
__global__ __launch_bounds__(512) void scan_bsums_k(int* __restrict__ bsums, int nb,
                                                    int* __restrict__ offsets, int N) {
    __shared__ int sh[512];
    int t = threadIdx.x;
    int v = (t < nb) ? bsums[t] : 0;
    sh[t] = v;
    __syncthreads();
    for (int off = 1; off < 512; off <<= 1) {
        int u = (t >= off) ? sh[t - off] : 0;
        __syncthreads();
        sh[t] += u;
        __syncthreads();
    }
    if (t < nb) bsums[t] = sh[t] - v;          // exclusive
    if (t == nb - 1) offsets[N] = sh[t];       // total == E
}

__global__ __launch_bounds__(256) void scan_write_k(const int* __restrict__ deg,
                                                    const int* __restrict__ bsums,
                                                    int* __restrict__ offsets, int N) {
    __shared__ int sh[256];
    int i = blockIdx.x * 256 + threadIdx.x;
    int v = (i < N) ? deg[i] : 0;
    sh[threadIdx.x] = v;
    __syncthreads();
    for (int off = 1; off < 256; off <<= 1) {
        int t = (threadIdx.x >= (unsigned)off) ? sh[threadIdx.x - off] : 0;
        __syncthreads();
        sh[threadIdx.x] += t;
        __syncthreads();
    }
    if (i < N) offsets[i] = bsums[blockIdx.x] + sh[threadIdx.x] - v;  // exclusive
}

// Phase 1: compact edges into 8 dst-range buckets, packed (dl<<17)|src.
// Per block: 4096 edges in regs; per bucket r: wave-scan compaction -> LDS
// stage -> one atomicAdd on the bucket cursor -> coalesced flush.
#define P1_CHUNK 16   // edges per thread
__global__ __launch_bounds__(256) void partition_edges_k(const int* __restrict__ src,
                                                         const int* __restrict__ dst,
                                                         int* __restrict__ pcur,
                                                         int* __restrict__ pairs,
                                                         int E, int npp, int cap) {
    __shared__ int stage[256 * P1_CHUNK];
    __shared__ int wsum[4];
    __shared__ int base_sh;
    int tid = threadIdx.x;
    int lane = tid & 63, wid = tid >> 6;
    int e0 = blockIdx.x * 256 * P1_CHUNK;

    int bket[P1_CHUNK], pck[P1_CHUNK];
    #pragma unroll
    for (int k = 0; k < P1_CHUNK; k++) {
        int e = e0 + k * 256 + tid;
        bool valid = e < E;
        int d = valid ? __builtin_nontemporal_load(dst + e) : 0;
        int s = valid ? __builtin_nontemporal_load(src + e) : 0;
        int b = (d >= npp) + (d >= 2 * npp) + (d >= 3 * npp) + (d >= 4 * npp)
              + (d >= 5 * npp) + (d >= 6 * npp) + (d >= 7 * npp);
        bket[k] = valid ? b : -1;
        pck[k]  = ((d - b * npp) << 17) | s;
    }

    for (int r = 0; r < 8; r++) {
        int c = 0;
        #pragma unroll
        for (int k = 0; k < P1_CHUNK; k++) c += (bket[k] == r);
        // wave inclusive scan of c
        int sc = c;
        #pragma unroll
        for (int o = 1; o < 64; o <<= 1) {
            int t = __shfl_up(sc, o);
            if (lane >= o) sc += t;
        }
        if (lane == 63) wsum[wid] = sc;
        __syncthreads();
        int wbase = 0;
        for (int w = 0; w < 4; w++) wbase += (w < wid) ? wsum[w] : 0;
        int tot = wsum[0] + wsum[1] + wsum[2] + wsum[3];
        if (tid == 0 && tot > 0) base_sh = atomicAdd(&pcur[r], tot);
        __syncthreads();
        int my = wbase + sc - c;            // exclusive position in block
        #pragma unroll
        for (int k = 0; k < P1_CHUNK; k++)
            if (bket[k] == r) stage[my++] = pck[k];
        __syncthreads();
        if (tot > 0) {
            int gbase = base_sh;
            if (gbase + tot <= cap) {
                int* dstp = pairs + (size_t)r * cap + gbase;
                for (int i = tid; i < tot; i += 256)
                    __builtin_nontemporal_store(stage[i], dstp + i);
            }
        }
        __syncthreads();
    }
}

// Phase 2: each block discovers its physical XCD and scatters ONLY its own
// XCD's bucket into sorted_src (chunk-claim work loop, mapping-independent).
#define P2_CHUNK 1024
__global__ __launch_bounds__(256) void fill_from_parts_k(const int* __restrict__ pairs,
                                                         const int* __restrict__ pcur,
                                                         const int* __restrict__ offsets,
                                                         int* __restrict__ cursor,
                                                         int* __restrict__ sorted_src,
                                                         int* __restrict__ work,
                                                         int npp, int cap) {
    __shared__ int chunk_sh;
    unsigned xcc;
    asm volatile("s_getreg_b32 %0, hwreg(HW_REG_XCC_ID)" : "=s"(xcc));
    int p = (int)(xcc & 7);
    int cnt = pcur[p];
    if (cnt > cap) cnt = cap;
    int lo = p * npp;
    const int* plist = pairs + (size_t)p * cap;
    int tid = threadIdx.x;
    for (;;) {
        if (tid == 0) chunk_sh = atomicAdd(&work[p], P2_CHUNK);
        __syncthreads();
        int chunk = chunk_sh;
        __syncthreads();
        if (chunk >= cnt) break;
        int end = chunk + P2_CHUNK;
        if (end > cnt) end = cnt;
        for (int i = chunk + tid; i < end; i += 256) {
            int v = __builtin_nontemporal_load(plist + i);
            int d = lo + (v >> 17);
            int s = v & 0x1ffff;
            int pos = offsets[d] + atomicAdd(&cursor[d], 1);
            sorted_src[pos] = s;
        }
    }
}

// W (fp32 row-major [j][k]) -> bf16
__global__ __launch_bounds__(256) void prep_w_k(const float* __restrict__ W,
                                                unsigned short* __restrict__ wb) {
    int i = blockIdx.x * 256 + threadIdx.x;
    if (i < DIM * DIM) wb[i] = f2b(W[i]);
}

// feat_s[n][k] = bf16(norm[n] * feat[n][k]); one thread per 4 elems
__global__ __launch_bounds__(256) void prescale_k(const float* __restrict__ feat,
                                                  const int* __restrict__ offsets,
                                                  unsigned short* __restrict__ feat_s,
                                                  int N) {
    int idx = blockIdx.x * 256 + threadIdx.x;
    int total = N * (DIM / 4);
    if (idx >= total) return;
    int n = idx >> 5;                      // /(DIM/4)
    int dgi = offsets[n + 1] - offsets[n];
    float dg = (float)(dgi < 1 ? 1 : dgi);
    float nrm = rsqrtf(dg);
    float4 f = ((const float4*)feat)[idx];
    unsigned lo = (unsigned)f2b(f.x * nrm) | ((unsigned)f2b(f.y * nrm) << 16);
    unsigned hi = (unsigned)f2b(f.z * nrm) | ((unsigned)f2b(f.w * nrm) << 16);
    ((uint2*)feat_s)[idx] = make_uint2(lo, hi);
}

// one wave per node: gather-sum bf16 rows with 8-deep MLP pipelining
__global__ __launch_bounds__(256) void aggregate_k(const unsigned short* __restrict__ feat_s,
                                                   const int* __restrict__ offsets,
                                                   const int* __restrict__ sorted_src,
                                                   unsigned short* __restrict__ agg, int N) {
    int wave = (blockIdx.x * 256 + threadIdx.x) >> 6;
    int lane = threadIdx.x & 63;
    if (wave >= N) return;
    int s0 = __builtin_amdgcn_readfirstlane(offsets[wave]);
    int s1 = __builtin_amdgcn_readfirstlane(offsets[wave + 1]);
    float ax = 0.f, ay = 0.f;
    int i = s0;
    for (; i + 8 <= s1; i += 8) {
        int idx[8];
        #pragma unroll
        for (int k = 0; k < 8; k++) idx[k] = sorted_src[i + k];
        unsigned v[8];
        #pragma unroll
        for (int k = 0; k < 8; k++)
            v[k] = *(const unsigned*)(feat_s + (size_t)idx[k] * DIM + lane * 2);
        #pragma unroll
        for (int k = 0; k < 8; k++) {
            ax += __uint_as_float(v[k] << 16);
            ay += __uint_as_float(v[k] & 0xffff0000u);
        }
    }
    for (; i + 2 <= s1; i += 2) {
        int i0 = sorted_src[i], i1 = sorted_src[i + 1];
        unsigned v0 = *(const unsigned*)(feat_s + (size_t)i0 * DIM + lane * 2);
        unsigned v1 = *(const unsigned*)(feat_s + (size_t)i1 * DIM + lane * 2);
        ax += __uint_as_float(v0 << 16) + __uint_as_float(v1 << 16);
        ay += __uint_as_float(v0 & 0xffff0000u) + __uint_as_float(v1 & 0xffff0000u);
    }
    if (i < s1) {
        int i0 = sorted_src[i];
        unsigned v0 = *(const unsigned*)(feat_s + (size_t)i0 * DIM + lane * 2);
        ax += __uint_as_float(v0 << 16);
        ay += __uint_as_float(v0 & 0xffff0000u);
    }
    unsigned p = (unsigned)f2b(ax) | ((unsigned)f2b(ay) << 16);
    *(unsigned*)(agg + (size_t)wave * DIM + lane * 2) = p;
}

// GEMM: out = relu(0.5*norm*(agg @ W^T) + 0.5*init/deg + 0.5*feat)
__global__ __launch_bounds__(256) void gemm_ep_k(const unsigned short* __restrict__ agg,
                                                 const unsigned short* __restrict__ wb,
                                                 const int* __restrict__ offsets,
                                                 const float* __restrict__ feat,
                                                 const float* __restrict__ init,
                                                 float* __restrict__ out, int N) {
    int wid = threadIdx.x >> 6;
    int lane = threadIdx.x & 63;
    int row16 = lane & 15;
    int kb = lane >> 4;                 // 0..3, k block of 8
    int base_m = blockIdx.x * 128 + wid * 32;

    short8v afr[2][4];
    #pragma unroll
    for (int mt = 0; mt < 2; mt++) {
        int m = base_m + mt * 16 + row16;
        if (m >= N) m = N - 1;          // clamp; store is masked
        const short8v* ap = (const short8v*)(agg + (size_t)m * DIM);
        #pragma unroll
        for (int ks = 0; ks < 4; ks++) afr[mt][ks] = ap[ks * 4 + kb];
    }

    f32x4 acc[2][8] = {};
    #pragma unroll
    for (int ct = 0; ct < 8; ct++) {
        int j = ct * 16 + row16;        // B col = W row (B = W^T)
        const short8v* bp = (const short8v*)(wb + (size_t)j * DIM);
        #pragma unroll
        for (int ks = 0; ks < 4; ks++) {
            short8v bfr = bp[ks * 4 + kb];
            acc[0][ct] = __builtin_amdgcn_mfma_f32_16x16x32_bf16(afr[0][ks], bfr, acc[0][ct], 0, 0, 0);
            acc[1][ct] = __builtin_amdgcn_mfma_f32_16x16x32_bf16(afr[1][ks], bfr, acc[1][ct], 0, 0, 0);
        }
    }

    // epilogue: D layout col=lane&15, row=(lane>>4)*4+reg
    #pragma unroll
    for (int mt = 0; mt < 2; mt++) {
        int m0 = base_m + mt * 16 + (lane >> 4) * 4;
        #pragma unroll
        for (int r = 0; r < 4; r++) {
            int m = m0 + r;
            if (m >= N) continue;
            int dgi = offsets[m + 1] - offsets[m];
            float dg = (float)(dgi < 1 ? 1 : dgi);
            float nrm = rsqrtf(dg);
            float n1 = 1.0f / dg;
            #pragma unroll
            for (int ct = 0; ct < 8; ct++) {
                int j = ct * 16 + row16;
                float o = 0.5f * nrm * acc[mt][ct][r]
                        + 0.5f * n1 * init[(size_t)m * DIM + j]
                        + 0.5f * feat[(size_t)m * DIM + j];
                out[(size_t)m * DIM + j] = fmaxf(o, 0.f);
            }
        }
    }
}

extern "C" void kernel_launch(void* const* d_in, const int* in_sizes, int n_in,
                              void* d_out, int out_size, void* d_ws, size_t ws_size,
                              hipStream_t stream) {
    const float* feat = (const float*)d_in[0];
    const float* init = (const float*)d_in[1];
    const float* W    = (const float*)d_in[2];
    const int*   src  = (const int*)d_in[3];
    const int*   dst  = (const int*)d_in[4];
    const int N = in_sizes[0] / DIM;
    const int E = in_sizes[3];
    float* out = (float*)d_out;

    char* ws = (char*)d_ws;
    size_t o_deg = 0;
    size_t o_bs  = o_deg + (size_t)N * 4;
    size_t o_pc  = o_bs + 2048;                 // pcur[8]
    size_t o_wk  = o_pc + 32;                   // work[8]
    size_t o_off = o_wk + 32;
    size_t o_srt = (o_off + (size_t)(N + 1) * 4 + 127) & ~(size_t)127;
    size_t o_fs  = (o_srt + (size_t)E * 4 + 511) & ~(size_t)511;
    size_t o_agg = o_fs + (size_t)N * DIM * 2;
    size_t o_w   = o_agg + (size_t)N * DIM * 2;
    int*            deg        = (int*)(ws + o_deg);   // later reused as cursor
    int*            bsums      = (int*)(ws + o_bs);
    int*            pcur       = (int*)(ws + o_pc);
    int*            work       = (int*)(ws + o_wk);
    int*            offsets    = (int*)(ws + o_off);
    int*            sorted_src = (int*)(ws + o_srt);
    unsigned short* feat_s     = (unsigned short*)(ws + o_fs);
    unsigned short* agg        = (unsigned short*)(ws + o_agg);
    unsigned short* wb         = (unsigned short*)(ws + o_w);
    int*            pairs      = (int*)(ws + o_agg);   // alias: agg written later

    const int nb = (N + 255) / 256;
    const int eb = (E + 255) / 256;
    const int npp = (N + 7) / 8;          // nodes per XCD partition
    const int cap = E / 8 + 65536;        // bucket capacity (pairs = 8*cap*4 B)

    hipMemsetAsync(ws, 0, o_off, stream);             // deg + bsums + pcur + work
    count_deg_k<<<eb, 256, 0, stream>>>(dst, deg, E);
    block_sums_k<<<nb, 256, 0, stream>>>(deg, bsums, N);
    scan_bsums_k<<<1, 512, 0, stream>>>(bsums, nb, offsets, N);
    scan_write_k<<<nb, 256, 0, stream>>>(deg, bsums, offsets, N);
    hipMemsetAsync(deg, 0, (size_t)N * 4, stream);    // reuse as cursor

    int p1b = (E + 256 * P1_CHUNK - 1) / (256 * P1_CHUNK);
    partition_edges_k<<<p1b, 256, 0, stream>>>(src, dst, pcur, pairs, E, npp, cap);
    fill_from_parts_k<<<2048, 256, 0, stream>>>(pairs, pcur, offsets, deg,
                                                sorted_src, work, npp, cap);

    prep_w_k<<<(DIM * DIM + 255) / 256, 256, 0, stream>>>(W, wb);
    prescale_k<<<(N * (DIM / 4) + 255) / 256, 256, 0, stream>>>(feat, offsets, feat_s, N);
    aggregate_k<<<(int)(((size_t)N * 64 + 255) / 256), 256, 0, stream>>>(
        feat_s, offsets, sorted_src, agg, N);
    gemm_ep_k<<<(N + 127) / 128, 256, 0, stream>>>(agg, wb, offsets, feat, init, out, N);
}